// Round 4
// baseline (1717.730 us; speedup 1.0000x reference)
//
#include <hip/hip_runtime.h>

typedef unsigned short u16;
typedef unsigned int   u32;
typedef _Float16       f16;
typedef f16   f16x2  __attribute__((ext_vector_type(2)));
typedef f16   f16x8  __attribute__((ext_vector_type(8)));
typedef float f32x4  __attribute__((ext_vector_type(4)));
typedef u32   u32x2  __attribute__((ext_vector_type(2)));
typedef u32   u32x4  __attribute__((ext_vector_type(4)));

#define MDIM 8192
#define KDIM 4096
#define NDIM 11008
#define NKT  64    // K / 64
#define LDA  72    // padded A row stride in u16: 64 k + 8 pad; row*144B keeps 16B align, banks 2-way-free

// Tile: BM=256 x BN=128, 512 threads = 8 waves in a 4x2 grid, each wave owns 64x64.
// Rationale: B-dequant VALU per thread halves vs 128x128/256t; MFMA per thread unchanged.

__global__ __launch_bounds__(512) void int4_gemm(
    const float* __restrict__ x,     // [M][K] f32 (harness materializes fp16 as f32)
    const int*   __restrict__ wpk,   // [K/2][N] packed nibbles (low = even k, high = odd k)
    const float* __restrict__ sc,    // [K/128][N] f32
    const float* __restrict__ bias,  // [N] f32
    float*       __restrict__ out)   // [M][N] f32
{
    __shared__ __align__(16) u16 ldsA[256 * LDA];  // 36 KB, padded row-major [m][k] fp16
    __shared__ __align__(16) u16 ldsB[8192];       // 16 KB, fragment-ordered:
                                                   //   chunk = ks*512 + quad*128 + n -> 8 fp16 (8 consecutive k)

    const int tid  = threadIdx.x;
    const int wave = tid >> 6;
    const int lane = tid & 63;
    const int wm   = wave >> 1;          // 4x2 wave grid; each wave owns 64x64 of the 256x128 tile
    const int wn   = wave & 1;
    const int quad = lane >> 4;
    const int l15  = lane & 15;

    // XCD-aware bijective swizzle: grid = 86*32 = 2752 = 8 * 344 (exact).
    // Blocks on one XCD get 4 consecutive m-panels, walking n fastest -> A-panel L2 reuse.
    const int bid   = blockIdx.y * 86 + blockIdx.x;
    const int swz   = (bid & 7) * 344 + (bid >> 3);
    const int n_blk = swz % 86;
    const int m_blk = swz / 86;
    const int m0    = m_blk * 256;
    const int n0    = n_blk * 128;

    // B staging: thread -> one column n, 8 packed rows (k = half*16 .. half*16+15 of the tile)
    const int n_local = tid & 127;
    const int half    = tid >> 7;        // 0..3
    const int gn      = n0 + n_local;

    f32x4 acc[4][4];
    const f32x4 zero4 = {0.f, 0.f, 0.f, 0.f};
#pragma unroll
    for (int mt = 0; mt < 4; ++mt)
#pragma unroll
        for (int nt = 0; nt < 4; ++nt) acc[mt][nt] = zero4;

    // ---- prefetch tile 0 ----
    // A: 8 passes; pass p: chunk id c = p*512+tid, row = c>>4 (0..255), kchunk = c&15 (4 f32 each)
    f32x4 areg[8];
    int   pw[8];
    float scur;
    {
#pragma unroll
        for (int p = 0; p < 8; ++p) {
            const int c = p * 512 + tid;
            areg[p] = *(const f32x4*)(x + (size_t)(m0 + (c >> 4)) * KDIM + (c & 15) * 4);
        }
        const int kp0 = half * 8;
#pragma unroll
        for (int i = 0; i < 8; ++i) pw[i] = wpk[(kp0 + i) * NDIM + gn];
        scur = sc[gn];
    }

    for (int kt = 0; kt < NKT; ++kt) {
        // ---- dequant packed W regs -> ldsB (fragment order, fp16) ----
        // fp16 magic: 0x6400|q == 1024+q (exact). (1024+q) - 1032 == q-8 (EXACT fp16
        // subtraction, small integers). Then (q-8)*s is one v_pk_mul_f16, single
        // rounding -> bit-identical to reference's fp16 dequant.
        {
            const f16 sh = (f16)scur;
            const f16x2 s2 = {sh, sh};
            const f16x2 cm = {(f16)(-1032.0f), (f16)(-1032.0f)};
#pragma unroll
            for (int g = 0; g < 2; ++g) {
                u32 wds[4];
#pragma unroll
                for (int r = 0; r < 4; ++r) {
                    const u32 w = (u32)pw[g * 4 + r];
                    const u32 hbits = 0x64006400u | (w & 15u) | ((w & 0xF0u) << 12);
                    const f16x2 hv = __builtin_bit_cast(f16x2, hbits);
                    const f16x2 rr = (hv + cm) * s2;   // pk_add (exact) + pk_mul
                    wds[r] = __builtin_bit_cast(u32, rr);
                }
                // packed-row base p = half*8 + g*4 -> ks = p>>4, quad = (p&15)>>2
                const int ks_s   = half >> 1;
                const int quad_s = (half & 1) * 2 + g;
                u32x4 wv = {wds[0], wds[1], wds[2], wds[3]};
                *(u32x4*)&ldsB[(ks_s * 512 + quad_s * 128 + n_local) * 8] = wv;
            }
        }

        // ---- A regs: f32x4 -> packed fp16 via cvt_pkrtz (exact: x is exactly-fp16) ----
#pragma unroll
        for (int p = 0; p < 8; ++p) {
            const int c   = p * 512 + tid;
            const int row = c >> 4;
            const int kc  = c & 15;
            u32x2 v;
            v.x = __builtin_bit_cast(u32, __builtin_amdgcn_cvt_pkrtz(areg[p][0], areg[p][1]));
            v.y = __builtin_bit_cast(u32, __builtin_amdgcn_cvt_pkrtz(areg[p][2], areg[p][3]));
            *(u32x2*)&ldsA[row * LDA + kc * 4] = v;
        }

        __syncthreads();   // barrier 1: A + B tiles visible

        // ---- prefetch next tile under the MFMA shadow ----
        if (kt + 1 < NKT) {
#pragma unroll
            for (int p = 0; p < 8; ++p) {
                const int c = p * 512 + tid;
                areg[p] = *(const f32x4*)(x + (size_t)(m0 + (c >> 4)) * KDIM
                                            + (kt + 1) * 64 + (c & 15) * 4);
            }
            const int kp0 = (kt + 1) * 32 + half * 8;
#pragma unroll
            for (int i = 0; i < 8; ++i) pw[i] = wpk[(kp0 + i) * NDIM + gn];
            scur = sc[((kt + 1) >> 1) * NDIM + gn];
        }

        // ---- compute: 2 ksteps x (4 A-frags, 4 B-frags, 16 MFMA) ----
#pragma unroll
        for (int ks = 0; ks < 2; ++ks) {
            f16x8 af[4], bfr[4];
#pragma unroll
            for (int mt = 0; mt < 4; ++mt)
                af[mt] = *(const f16x8*)&ldsA[(wm * 64 + mt * 16 + l15) * LDA
                                              + ks * 32 + quad * 8];
#pragma unroll
            for (int nt = 0; nt < 4; ++nt)
                bfr[nt] = *(const f16x8*)&ldsB[(ks * 512 + quad * 128 + wn * 64 + nt * 16 + l15) * 8];
#pragma unroll
            for (int mt = 0; mt < 4; ++mt)
#pragma unroll
                for (int nt = 0; nt < 4; ++nt)
                    acc[mt][nt] = __builtin_amdgcn_mfma_f32_16x16x32_f16(
                        af[mt], bfr[nt], acc[mt][nt], 0, 0, 0);
        }

        __syncthreads();   // barrier 2: LDS free for next iteration
    }

    // ---- epilogue: + bias, f32 store ----
    float bv[4];
#pragma unroll
    for (int nt = 0; nt < 4; ++nt)
        bv[nt] = bias[n0 + wn * 64 + nt * 16 + l15];
#pragma unroll
    for (int mt = 0; mt < 4; ++mt) {
        const int row = m0 + wm * 64 + mt * 16 + quad * 4;   // C/D: row = quad*4 + r, col = lane&15
#pragma unroll
        for (int nt = 0; nt < 4; ++nt) {
            const int col = n0 + wn * 64 + nt * 16 + l15;
#pragma unroll
            for (int r = 0; r < 4; ++r)
                out[(size_t)(row + r) * NDIM + col] = acc[mt][nt][r] + bv[nt];
        }
    }
}

extern "C" void kernel_launch(void* const* d_in, const int* in_sizes, int n_in,
                              void* d_out, int out_size, void* d_ws, size_t ws_size,
                              hipStream_t stream) {
    const float* x    = (const float*)d_in[0];
    const int*   wpk  = (const int*)d_in[1];
    const float* scl  = (const float*)d_in[2];
    const float* bias = (const float*)d_in[3];
    // d_in[4] = group_size (=128), baked in
    dim3 grid(NDIM / 128, MDIM / 256);   // 86 x 32 = 2752 blocks (8 XCDs x 344)
    int4_gemm<<<grid, dim3(512), 0, stream>>>(x, wpk, scl, bias, (float*)d_out);
}

// Round 5
// 1508.396 us; speedup vs baseline: 1.1388x; 1.1388x over previous
//
#include <hip/hip_runtime.h>

typedef unsigned short u16;
typedef unsigned int   u32;
typedef _Float16       f16;
typedef f16   f16x2  __attribute__((ext_vector_type(2)));
typedef f16   f16x8  __attribute__((ext_vector_type(8)));
typedef float f32x4  __attribute__((ext_vector_type(4)));
typedef u32   u32x2  __attribute__((ext_vector_type(2)));
typedef u32   u32x4  __attribute__((ext_vector_type(4)));

#define MDIM 8192
#define KDIM 4096
#define NDIM 11008
#define NKT  64    // K / 64
#define LDA  72    // padded A row stride in u16: 64 k + 8 pad
#define ABUF (128 * LDA)   // 9216 u16 per A buffer
#define BBUF 8192          // u16 per B buffer

// 128x128 tile, 256 threads (2x2 waves, 64x64 each) — best-measured geometry (R3).
// Double-buffered LDS, ONE barrier per K-tile: stage(kt+1)->buf^1 overlaps compute(kt)->buf.

__global__ __launch_bounds__(256) void int4_gemm(
    const float* __restrict__ x,     // [M][K] f32 (harness materializes fp16 as f32)
    const int*   __restrict__ wpk,   // [K/2][N] packed nibbles (low = even k, high = odd k)
    const float* __restrict__ sc,    // [K/128][N] f32
    const float* __restrict__ bias,  // [N] f32
    float*       __restrict__ out)   // [M][N] f32
{
    __shared__ __align__(16) u16 ldsA[2 * ABUF];  // 36 KB
    __shared__ __align__(16) u16 ldsB[2 * BBUF];  // 32 KB   (68 KB total, 2 blocks/CU)

    const int tid  = threadIdx.x;
    const int wave = tid >> 6;
    const int lane = tid & 63;
    const int wm   = wave >> 1;
    const int wn   = wave & 1;
    const int quad = lane >> 4;
    const int l15  = lane & 15;

    // XCD-aware bijective swizzle: grid = 86*64 = 5504 = 8 * 688 (exact).
    // Consecutive blocks on one XCD walk n fastest within an 8-m-row chunk -> A/B L2 reuse.
    const int bid   = blockIdx.y * 86 + blockIdx.x;
    const int swz   = (bid & 7) * 688 + (bid >> 3);
    const int n_blk = swz % 86;
    const int m_blk = swz / 86;
    const int m0    = m_blk * 128;
    const int n0    = n_blk * 128;

    // B staging: thread -> one column n, 16 packed rows (k = half*32 .. half*32+31 of tile)
    const int n_local = tid & 127;
    const int half    = tid >> 7;
    const int gn      = n0 + n_local;

    f32x4 acc[4][4];
    const f32x4 zero4 = {0.f, 0.f, 0.f, 0.f};
#pragma unroll
    for (int mt = 0; mt < 4; ++mt)
#pragma unroll
        for (int nt = 0; nt < 4; ++nt) acc[mt][nt] = zero4;

    f32x4 areg[8];
    int   pw[16];
    float scur;

    // ---- prologue: load tile 0, stage into buf0, then prefetch tile 1 ----
#pragma unroll
    for (int p = 0; p < 8; ++p) {
        const int c = p * 256 + tid;
        areg[p] = *(const f32x4*)(x + (size_t)(m0 + (c >> 4)) * KDIM + (c & 15) * 4);
    }
#pragma unroll
    for (int i = 0; i < 16; ++i) pw[i] = wpk[(half * 16 + i) * NDIM + gn];
    scur = sc[gn];

    {   // stage tile 0 -> buffer 0
        const f16 sh = (f16)scur;
        const f16x2 s2 = {sh, sh};
        const f16x2 cm = {(f16)(-1032.0f), (f16)(-1032.0f)};
#pragma unroll
        for (int q = 0; q < 4; ++q) {
            u32 wds[4];
#pragma unroll
            for (int r = 0; r < 4; ++r) {
                const u32 w = (u32)pw[q * 4 + r];
                const u32 hbits = 0x64006400u | (w & 15u) | ((w & 0xF0u) << 12);
                const f16x2 hv = __builtin_bit_cast(f16x2, hbits);
                const f16x2 rr = (hv + cm) * s2;
                wds[r] = __builtin_bit_cast(u32, rr);
            }
            u32x4 wv = {wds[0], wds[1], wds[2], wds[3]};
            *(u32x4*)&ldsB[(half * 512 + q * 128 + n_local) * 8] = wv;
        }
#pragma unroll
        for (int p = 0; p < 8; ++p) {
            const int c = p * 256 + tid;
            u32x2 v;
            v.x = __builtin_bit_cast(u32, __builtin_amdgcn_cvt_pkrtz(areg[p][0], areg[p][1]));
            v.y = __builtin_bit_cast(u32, __builtin_amdgcn_cvt_pkrtz(areg[p][2], areg[p][3]));
            *(u32x2*)&ldsA[(c >> 4) * LDA + (c & 15) * 4] = v;
        }
    }

    // prefetch tile 1 into regs (after staging consumed tile-0 regs)
#pragma unroll
    for (int p = 0; p < 8; ++p) {
        const int c = p * 256 + tid;
        areg[p] = *(const f32x4*)(x + (size_t)(m0 + (c >> 4)) * KDIM + 64 + (c & 15) * 4);
    }
#pragma unroll
    for (int i = 0; i < 16; ++i) pw[i] = wpk[(32 + half * 16 + i) * NDIM + gn];
    scur = sc[gn];   // group 0 still covers k < 128

    __syncthreads();

    for (int kt = 0; kt < NKT; ++kt) {
        const int cur = kt & 1;
        const u16* asrc = ldsA + cur * ABUF;
        const u16* bsrc = ldsB + cur * BBUF;

        // ---- stage tile kt+1 into the other buffer (overlaps compute below) ----
        if (kt + 1 < NKT) {
            u16* adst = ldsA + (cur ^ 1) * ABUF;
            u16* bdst = ldsB + (cur ^ 1) * BBUF;
            // fp16 magic dequant: 0x6400|q == 1024+q (exact); (1024+q)-1032 == q-8
            // (exact fp16 sub); then one pk_mul by s -> single rounding.
            const f16 sh = (f16)scur;
            const f16x2 s2 = {sh, sh};
            const f16x2 cm = {(f16)(-1032.0f), (f16)(-1032.0f)};
#pragma unroll
            for (int q = 0; q < 4; ++q) {
                u32 wds[4];
#pragma unroll
                for (int r = 0; r < 4; ++r) {
                    const u32 w = (u32)pw[q * 4 + r];
                    const u32 hbits = 0x64006400u | (w & 15u) | ((w & 0xF0u) << 12);
                    const f16x2 hv = __builtin_bit_cast(f16x2, hbits);
                    const f16x2 rr = (hv + cm) * s2;
                    wds[r] = __builtin_bit_cast(u32, rr);
                }
                u32x4 wv = {wds[0], wds[1], wds[2], wds[3]};
                *(u32x4*)&bdst[(half * 512 + q * 128 + n_local) * 8] = wv;
            }
#pragma unroll
            for (int p = 0; p < 8; ++p) {
                const int c = p * 256 + tid;
                u32x2 v;
                v.x = __builtin_bit_cast(u32, __builtin_amdgcn_cvt_pkrtz(areg[p][0], areg[p][1]));
                v.y = __builtin_bit_cast(u32, __builtin_amdgcn_cvt_pkrtz(areg[p][2], areg[p][3]));
                *(u32x2*)&adst[(c >> 4) * LDA + (c & 15) * 4] = v;
            }
            // ---- prefetch tile kt+2 into regs (regs now free) ----
            if (kt + 2 < NKT) {
#pragma unroll
                for (int p = 0; p < 8; ++p) {
                    const int c = p * 256 + tid;
                    areg[p] = *(const f32x4*)(x + (size_t)(m0 + (c >> 4)) * KDIM
                                                + (kt + 2) * 64 + (c & 15) * 4);
                }
                const int kp0 = (kt + 2) * 32 + half * 16;
#pragma unroll
                for (int i = 0; i < 16; ++i) pw[i] = wpk[(kp0 + i) * NDIM + gn];
                scur = sc[((kt + 2) >> 1) * NDIM + gn];
            }
        }

        // ---- compute from buf[cur]: 2 ksteps x 16 MFMA ----
#pragma unroll
        for (int ks = 0; ks < 2; ++ks) {
            f16x8 af[4], bfr[4];
#pragma unroll
            for (int mt = 0; mt < 4; ++mt)
                af[mt] = *(const f16x8*)&asrc[(wm * 64 + mt * 16 + l15) * LDA
                                              + ks * 32 + quad * 8];
#pragma unroll
            for (int nt = 0; nt < 4; ++nt)
                bfr[nt] = *(const f16x8*)&bsrc[(ks * 512 + quad * 128 + wn * 64 + nt * 16 + l15) * 8];
#pragma unroll
            for (int mt = 0; mt < 4; ++mt)
#pragma unroll
                for (int nt = 0; nt < 4; ++nt)
                    acc[mt][nt] = __builtin_amdgcn_mfma_f32_16x16x32_f16(
                        af[mt], bfr[nt], acc[mt][nt], 0, 0, 0);
        }

        if (kt + 1 < NKT) __syncthreads();   // single barrier per K-tile
    }

    // ---- epilogue: + bias, f32 store ----
    float bv[4];
#pragma unroll
    for (int nt = 0; nt < 4; ++nt)
        bv[nt] = bias[n0 + wn * 64 + nt * 16 + l15];
#pragma unroll
    for (int mt = 0; mt < 4; ++mt) {
        const int row = m0 + wm * 64 + mt * 16 + quad * 4;   // C/D: row = quad*4 + r, col = lane&15
#pragma unroll
        for (int nt = 0; nt < 4; ++nt) {
            const int col = n0 + wn * 64 + nt * 16 + l15;
#pragma unroll
            for (int r = 0; r < 4; ++r)
                out[(size_t)(row + r) * NDIM + col] = acc[mt][nt][r] + bv[nt];
        }
    }
}

extern "C" void kernel_launch(void* const* d_in, const int* in_sizes, int n_in,
                              void* d_out, int out_size, void* d_ws, size_t ws_size,
                              hipStream_t stream) {
    const float* x    = (const float*)d_in[0];
    const int*   wpk  = (const int*)d_in[1];
    const float* scl  = (const float*)d_in[2];
    const float* bias = (const float*)d_in[3];
    // d_in[4] = group_size (=128), baked in
    dim3 grid(NDIM / 128, MDIM / 128);   // 86 x 64 = 5504 blocks (8 XCDs x 688)
    int4_gemm<<<grid, dim3(256), 0, stream>>>(x, wpk, scl, bias, (float*)d_out);
}

// Round 6
// 1347.702 us; speedup vs baseline: 1.2746x; 1.1192x over previous
//
#include <hip/hip_runtime.h>

typedef unsigned short u16;
typedef unsigned int   u32;
typedef _Float16       f16;
typedef f16   f16x2  __attribute__((ext_vector_type(2)));
typedef f16   f16x8  __attribute__((ext_vector_type(8)));
typedef float f32x4  __attribute__((ext_vector_type(4)));
typedef u32   u32x2  __attribute__((ext_vector_type(2)));
typedef u32   u32x4  __attribute__((ext_vector_type(4)));

#define MDIM 8192
#define KDIM 4096
#define NDIM 11008
#define NKT  64    // K / 64

// workspace plan: x16 (fp16 [M][K], 64 MB) at +0 ; w16 (fp16 chunked [K/8][N][8], 90.2 MB) at +64MB
#define X16_BYTES  67108864ull
#define W16_BYTES  90177536ull
#define WS_NEEDED  (X16_BYTES + W16_BYTES)

typedef const __attribute__((address_space(1))) u32 gu32;
typedef __attribute__((address_space(3)))       u32 su32;

// ---------------- pre-pass 1: x f32 -> fp16 row-major ----------------
__global__ __launch_bounds__(256) void cvt_x(const float* __restrict__ x, u16* __restrict__ x16)
{
    const size_t i = ((size_t)blockIdx.x * 256 + threadIdx.x) * 8;
    f32x4 a = *(const f32x4*)(x + i);
    f32x4 b = *(const f32x4*)(x + i + 4);
    u32x4 v;
    v.x = __builtin_bit_cast(u32, __builtin_amdgcn_cvt_pkrtz(a[0], a[1]));
    v.y = __builtin_bit_cast(u32, __builtin_amdgcn_cvt_pkrtz(a[2], a[3]));
    v.z = __builtin_bit_cast(u32, __builtin_amdgcn_cvt_pkrtz(b[0], b[1]));
    v.w = __builtin_bit_cast(u32, __builtin_amdgcn_cvt_pkrtz(b[2], b[3]));
    *(u32x4*)(x16 + i) = v;
}

// ---------------- pre-pass 2: W int4 -> fp16, chunked [kb=k/8][n][8] ----------------
// chunk (kb,n) holds k = kb*8 .. kb*8+7 for column n (16B contiguous).
// fp16 magic: 0x6400|q == 1024+q (exact); (1024+q)-1032 == q-8 (exact); * s single rounding
// -> bit-identical to the in-loop dequant that passed at absmax 0.0625.
__global__ __launch_bounds__(256) void dq_w(const int* __restrict__ wpk,
                                            const float* __restrict__ sc,
                                            u16* __restrict__ w16)
{
    const int kb = blockIdx.x / 43;                    // 0..511   (NDIM/256 = 43)
    const int n  = (blockIdx.x % 43) * 256 + threadIdx.x;
    const f16 sh = (f16)sc[(kb >> 4) * NDIM + n];      // group = k/128 = kb/16
    const f16x2 s2 = {sh, sh};
    const f16x2 cm = {(f16)(-1032.0f), (f16)(-1032.0f)};
    u32 wds[4];
#pragma unroll
    for (int j = 0; j < 4; ++j) {                      // packed row kp = kb*4+j -> k = 2kp,2kp+1
        const u32 w = (u32)wpk[(size_t)(kb * 4 + j) * NDIM + n];
        const u32 hb = 0x64006400u | (w & 15u) | ((w & 0xF0u) << 12);
        const f16x2 rr = (__builtin_bit_cast(f16x2, hb) + cm) * s2;
        wds[j] = __builtin_bit_cast(u32, rr);
    }
    u32x4 v = {wds[0], wds[1], wds[2], wds[3]};
    *(u32x4*)(w16 + ((size_t)kb * NDIM + n) * 8) = v;
}

// ---------------- main: pure fp16 GEMM, m97 structure ----------------
// 128x128 tile, BK=64, 256 threads (2x2 waves, 64x64/wave), global_load_lds for A and B.
// LDS A: chunk(row,kcl) 16B, logical kc = kcl ^ (row&7)  (T2 swizzle; inverse applied on
//        the GLOBAL source so the linear gload_lds destination lands swizzled — rule #21).
// LDS B: chunk(kbl,nl) 16B, linear (lane-consecutive n => conflict-free reads).
__global__ __launch_bounds__(256, 4) void gemm_f16(
    const u16* __restrict__ x16,   // [M][K] fp16
    const u16* __restrict__ w16,   // [K/8][N][8] fp16
    const float* __restrict__ bias,
    float*       __restrict__ out)
{
    __shared__ __align__(16) u16 ldsA[128 * 64];   // 16 KB
    __shared__ __align__(16) u16 ldsB[64 * 128];   // 16 KB  (32 KB total -> 4 blocks/CU)

    const int tid  = threadIdx.x;
    const int wave = tid >> 6;
    const int lane = tid & 63;
    const int wm   = wave >> 1;
    const int wn   = wave & 1;
    const int quad = lane >> 4;
    const int l15  = lane & 15;

    // XCD-aware bijective swizzle: 5504 = 8 * 688 exact
    const int bid   = blockIdx.y * 86 + blockIdx.x;
    const int swz   = (bid & 7) * 688 + (bid >> 3);
    const int n_blk = swz % 86;
    const int m_blk = swz / 86;
    const int m0    = m_blk * 128;
    const int n0    = n_blk * 128;

    f32x4 acc[4][4];
    const f32x4 zero4 = {0.f, 0.f, 0.f, 0.f};
#pragma unroll
    for (int mt = 0; mt < 4; ++mt)
#pragma unroll
        for (int nt = 0; nt < 4; ++nt) acc[mt][nt] = zero4;

    // staging address bases (4 passes x 16B per thread per operand)
    const u16* aglb[4];
    const u16* bglb[4];
#pragma unroll
    for (int p = 0; p < 4; ++p) {
        const int c   = p * 256 + tid;
        const int row = c >> 3;                 // 0..127
        const int kcl = c & 7;                  // LDS chunk slot
        const int kc  = kcl ^ (row & 7);        // pre-swizzled global source
        aglb[p] = x16 + (size_t)(m0 + row) * KDIM + kc * 8;
        const int kbl = c >> 7;                 // 0..7
        const int nl  = c & 127;
        bglb[p] = w16 + ((size_t)kbl * NDIM + n0 + nl) * 8;
    }
    u16* adst = ldsA + tid * 8;
    u16* bdst = ldsB + tid * 8;

    for (int kt = 0; kt < NKT; ++kt) {
        // ---- async stage tile kt (HBM/L2 -> LDS, no VGPR round-trip) ----
#pragma unroll
        for (int p = 0; p < 4; ++p)
            __builtin_amdgcn_global_load_lds((gu32*)(const void*)(aglb[p] + kt * 64),
                                             (su32*)(void*)(adst + p * 2048), 16, 0, 0);
#pragma unroll
        for (int p = 0; p < 4; ++p)
            __builtin_amdgcn_global_load_lds((gu32*)(const void*)(bglb[p] + (size_t)kt * NDIM * 64),
                                             (su32*)(void*)(bdst + p * 2048), 16, 0, 0);

        __syncthreads();   // barrier 1 (compiler drains vmcnt): tiles visible

        // ---- compute: 2 ksteps x 16 MFMA ----
#pragma unroll
        for (int ks = 0; ks < 2; ++ks) {
            f16x8 af[4], bfr[4];
#pragma unroll
            for (int mt = 0; mt < 4; ++mt) {
                const int mrow = wm * 64 + mt * 16 + l15;
                const int kcl  = (ks * 4 + quad) ^ (mrow & 7);   // swizzled read
                af[mt] = *(const f16x8*)&ldsA[(mrow * 8 + kcl) * 8];
            }
#pragma unroll
            for (int nt = 0; nt < 4; ++nt)
                bfr[nt] = *(const f16x8*)&ldsB[((ks * 4 + quad) * 128 + wn * 64 + nt * 16 + l15) * 8];
#pragma unroll
            for (int mt = 0; mt < 4; ++mt)
#pragma unroll
                for (int nt = 0; nt < 4; ++nt)
                    acc[mt][nt] = __builtin_amdgcn_mfma_f32_16x16x32_f16(
                        af[mt], bfr[nt], acc[mt][nt], 0, 0, 0);
        }

        __syncthreads();   // barrier 2: LDS free for next tile
    }

    // ---- epilogue: + bias, f32 store ----
    float bv[4];
#pragma unroll
    for (int nt = 0; nt < 4; ++nt)
        bv[nt] = bias[n0 + wn * 64 + nt * 16 + l15];
#pragma unroll
    for (int mt = 0; mt < 4; ++mt) {
        const int row = m0 + wm * 64 + mt * 16 + quad * 4;   // C/D: row = quad*4 + r, col = lane&15
#pragma unroll
        for (int nt = 0; nt < 4; ++nt) {
            const int col = n0 + wn * 64 + nt * 16 + l15;
#pragma unroll
            for (int r = 0; r < 4; ++r)
                out[(size_t)(row + r) * NDIM + col] = acc[mt][nt][r] + bv[nt];
        }
    }
}

// ---------------- fallback: R5 kernel (measured 1270 us profiled), used if ws too small ----------------
#define LDA  72
#define ABUF (128 * LDA)
#define BBUF 8192

__global__ __launch_bounds__(256) void int4_gemm_fb(
    const float* __restrict__ x, const int* __restrict__ wpk,
    const float* __restrict__ sc, const float* __restrict__ bias, float* __restrict__ out)
{
    __shared__ __align__(16) u16 ldsA[2 * ABUF];
    __shared__ __align__(16) u16 ldsB[2 * BBUF];

    const int tid  = threadIdx.x;
    const int wave = tid >> 6;
    const int lane = tid & 63;
    const int wm   = wave >> 1;
    const int wn   = wave & 1;
    const int quad = lane >> 4;
    const int l15  = lane & 15;
    const int bid   = blockIdx.y * 86 + blockIdx.x;
    const int swz   = (bid & 7) * 688 + (bid >> 3);
    const int n_blk = swz % 86;
    const int m_blk = swz / 86;
    const int m0    = m_blk * 128;
    const int n0    = n_blk * 128;
    const int n_local = tid & 127;
    const int half    = tid >> 7;
    const int gn      = n0 + n_local;

    f32x4 acc[4][4];
    const f32x4 zero4 = {0.f, 0.f, 0.f, 0.f};
#pragma unroll
    for (int mt = 0; mt < 4; ++mt)
#pragma unroll
        for (int nt = 0; nt < 4; ++nt) acc[mt][nt] = zero4;

    f32x4 areg[8];
    int   pw[16];
    float scur;
#pragma unroll
    for (int p = 0; p < 8; ++p) {
        const int c = p * 256 + tid;
        areg[p] = *(const f32x4*)(x + (size_t)(m0 + (c >> 4)) * KDIM + (c & 15) * 4);
    }
#pragma unroll
    for (int i = 0; i < 16; ++i) pw[i] = wpk[(half * 16 + i) * NDIM + gn];
    scur = sc[gn];
    {
        const f16 sh = (f16)scur;
        const f16x2 s2 = {sh, sh};
        const f16x2 cm = {(f16)(-1032.0f), (f16)(-1032.0f)};
#pragma unroll
        for (int q = 0; q < 4; ++q) {
            u32 wds[4];
#pragma unroll
            for (int r = 0; r < 4; ++r) {
                const u32 w = (u32)pw[q * 4 + r];
                const u32 hb = 0x64006400u | (w & 15u) | ((w & 0xF0u) << 12);
                const f16x2 rr = (__builtin_bit_cast(f16x2, hb) + cm) * s2;
                wds[r] = __builtin_bit_cast(u32, rr);
            }
            u32x4 wv = {wds[0], wds[1], wds[2], wds[3]};
            *(u32x4*)&ldsB[(half * 512 + q * 128 + n_local) * 8] = wv;
        }
#pragma unroll
        for (int p = 0; p < 8; ++p) {
            const int c = p * 256 + tid;
            u32x2 v;
            v.x = __builtin_bit_cast(u32, __builtin_amdgcn_cvt_pkrtz(areg[p][0], areg[p][1]));
            v.y = __builtin_bit_cast(u32, __builtin_amdgcn_cvt_pkrtz(areg[p][2], areg[p][3]));
            *(u32x2*)&ldsA[(c >> 4) * LDA + (c & 15) * 4] = v;
        }
    }
#pragma unroll
    for (int p = 0; p < 8; ++p) {
        const int c = p * 256 + tid;
        areg[p] = *(const f32x4*)(x + (size_t)(m0 + (c >> 4)) * KDIM + 64 + (c & 15) * 4);
    }
#pragma unroll
    for (int i = 0; i < 16; ++i) pw[i] = wpk[(32 + half * 16 + i) * NDIM + gn];
    scur = sc[gn];
    __syncthreads();

    for (int kt = 0; kt < NKT; ++kt) {
        const int cur = kt & 1;
        const u16* asrc = ldsA + cur * ABUF;
        const u16* bsrc = ldsB + cur * BBUF;
        if (kt + 1 < NKT) {
            u16* adst = ldsA + (cur ^ 1) * ABUF;
            u16* bdst = ldsB + (cur ^ 1) * BBUF;
            const f16 sh = (f16)scur;
            const f16x2 s2 = {sh, sh};
            const f16x2 cm = {(f16)(-1032.0f), (f16)(-1032.0f)};
#pragma unroll
            for (int q = 0; q < 4; ++q) {
                u32 wds[4];
#pragma unroll
                for (int r = 0; r < 4; ++r) {
                    const u32 w = (u32)pw[q * 4 + r];
                    const u32 hb = 0x64006400u | (w & 15u) | ((w & 0xF0u) << 12);
                    const f16x2 rr = (__builtin_bit_cast(f16x2, hb) + cm) * s2;
                    wds[r] = __builtin_bit_cast(u32, rr);
                }
                u32x4 wv = {wds[0], wds[1], wds[2], wds[3]};
                *(u32x4*)&bdst[(half * 512 + q * 128 + n_local) * 8] = wv;
            }
#pragma unroll
            for (int p = 0; p < 8; ++p) {
                const int c = p * 256 + tid;
                u32x2 v;
                v.x = __builtin_bit_cast(u32, __builtin_amdgcn_cvt_pkrtz(areg[p][0], areg[p][1]));
                v.y = __builtin_bit_cast(u32, __builtin_amdgcn_cvt_pkrtz(areg[p][2], areg[p][3]));
                *(u32x2*)&adst[(c >> 4) * LDA + (c & 15) * 4] = v;
            }
            if (kt + 2 < NKT) {
#pragma unroll
                for (int p = 0; p < 8; ++p) {
                    const int c = p * 256 + tid;
                    areg[p] = *(const f32x4*)(x + (size_t)(m0 + (c >> 4)) * KDIM
                                                + (kt + 2) * 64 + (c & 15) * 4);
                }
                const int kp0 = (kt + 2) * 32 + half * 16;
#pragma unroll
                for (int i = 0; i < 16; ++i) pw[i] = wpk[(kp0 + i) * NDIM + gn];
                scur = sc[((kt + 2) >> 1) * NDIM + gn];
            }
        }
#pragma unroll
        for (int ks = 0; ks < 2; ++ks) {
            f16x8 af[4], bfr[4];
#pragma unroll
            for (int mt = 0; mt < 4; ++mt)
                af[mt] = *(const f16x8*)&asrc[(wm * 64 + mt * 16 + l15) * LDA + ks * 32 + quad * 8];
#pragma unroll
            for (int nt = 0; nt < 4; ++nt)
                bfr[nt] = *(const f16x8*)&bsrc[(ks * 512 + quad * 128 + wn * 64 + nt * 16 + l15) * 8];
#pragma unroll
            for (int mt = 0; mt < 4; ++mt)
#pragma unroll
                for (int nt = 0; nt < 4; ++nt)
                    acc[mt][nt] = __builtin_amdgcn_mfma_f32_16x16x32_f16(
                        af[mt], bfr[nt], acc[mt][nt], 0, 0, 0);
        }
        if (kt + 1 < NKT) __syncthreads();
    }

    float bv[4];
#pragma unroll
    for (int nt = 0; nt < 4; ++nt)
        bv[nt] = bias[n0 + wn * 64 + nt * 16 + l15];
#pragma unroll
    for (int mt = 0; mt < 4; ++mt) {
        const int row = m0 + wm * 64 + mt * 16 + quad * 4;
#pragma unroll
        for (int nt = 0; nt < 4; ++nt) {
            const int col = n0 + wn * 64 + nt * 16 + l15;
#pragma unroll
            for (int r = 0; r < 4; ++r)
                out[(size_t)(row + r) * NDIM + col] = acc[mt][nt][r] + bv[nt];
        }
    }
}

extern "C" void kernel_launch(void* const* d_in, const int* in_sizes, int n_in,
                              void* d_out, int out_size, void* d_ws, size_t ws_size,
                              hipStream_t stream) {
    const float* x    = (const float*)d_in[0];
    const int*   wpk  = (const int*)d_in[1];
    const float* scl  = (const float*)d_in[2];
    const float* bias = (const float*)d_in[3];
    // d_in[4] = group_size (=128), baked in

    if (d_ws != nullptr && ws_size >= WS_NEEDED) {
        u16* x16 = (u16*)d_ws;
        u16* w16 = (u16*)((char*)d_ws + X16_BYTES);
        cvt_x<<<dim3(16384), dim3(256), 0, stream>>>(x, x16);          // 33.5M elems / 8 per thread
        dq_w <<<dim3(22016), dim3(256), 0, stream>>>(wpk, scl, w16);   // 512*43 blocks
        dim3 grid(NDIM / 128, MDIM / 128);                             // 86 x 64 = 5504 = 8*688
        gemm_f16<<<grid, dim3(256), 0, stream>>>(x16, w16, bias, (float*)d_out);
    } else {
        dim3 grid(NDIM / 128, MDIM / 128);
        int4_gemm_fb<<<grid, dim3(256), 0, stream>>>(x, wpk, scl, bias, (float*)d_out);
    }
}

// Round 7
// 1102.991 us; speedup vs baseline: 1.5573x; 1.2219x over previous
//
#include <hip/hip_runtime.h>

typedef unsigned short u16;
typedef unsigned int   u32;
typedef _Float16       f16;
typedef f16   f16x2  __attribute__((ext_vector_type(2)));
typedef f16   f16x8  __attribute__((ext_vector_type(8)));
typedef float f32x4  __attribute__((ext_vector_type(4)));
typedef u32   u32x2  __attribute__((ext_vector_type(2)));
typedef u32   u32x4  __attribute__((ext_vector_type(4)));

#define MDIM 8192
#define KDIM 4096
#define NDIM 11008
#define NKT  64    // K / 64

// workspace: x16 (fp16 [M][K], 64 MB) @ +0 ; w16 (fp16 chunked [K/8][N][8], 90.2 MB) @ +64MB
#define X16_BYTES  67108864ull
#define W16_BYTES  90177536ull
#define WS_NEEDED  (X16_BYTES + W16_BYTES)

typedef const __attribute__((address_space(1))) u32 gu32;
typedef __attribute__((address_space(3)))       u32 su32;

// ---------------- pre-pass 1: x f32 -> fp16 row-major ----------------
__global__ __launch_bounds__(256) void cvt_x(const float* __restrict__ x, u16* __restrict__ x16)
{
    const size_t i = ((size_t)blockIdx.x * 256 + threadIdx.x) * 8;
    f32x4 a = *(const f32x4*)(x + i);
    f32x4 b = *(const f32x4*)(x + i + 4);
    u32x4 v;
    v.x = __builtin_bit_cast(u32, __builtin_amdgcn_cvt_pkrtz(a[0], a[1]));
    v.y = __builtin_bit_cast(u32, __builtin_amdgcn_cvt_pkrtz(a[2], a[3]));
    v.z = __builtin_bit_cast(u32, __builtin_amdgcn_cvt_pkrtz(b[0], b[1]));
    v.w = __builtin_bit_cast(u32, __builtin_amdgcn_cvt_pkrtz(b[2], b[3]));
    *(u32x4*)(x16 + i) = v;
}

// ---------------- pre-pass 2: W int4 -> fp16, chunked [kb=k/8][n][8] ----------------
// fp16 magic: 0x6400|q == 1024+q (exact); (1024+q)-1032 == q-8 (exact fp16 sub);
// * s single rounding -> bit-identical to the verified in-loop dequant (absmax 0.0625).
__global__ __launch_bounds__(256) void dq_w(const int* __restrict__ wpk,
                                            const float* __restrict__ sc,
                                            u16* __restrict__ w16)
{
    const int kb = blockIdx.x / 43;                    // 0..511   (NDIM/256 = 43)
    const int n  = (blockIdx.x % 43) * 256 + threadIdx.x;
    const f16 sh = (f16)sc[(kb >> 4) * NDIM + n];      // group = k/128 = kb/16
    const f16x2 s2 = {sh, sh};
    const f16x2 cm = {(f16)(-1032.0f), (f16)(-1032.0f)};
    u32 wds[4];
#pragma unroll
    for (int j = 0; j < 4; ++j) {
        const u32 w = (u32)wpk[(size_t)(kb * 4 + j) * NDIM + n];
        const u32 hb = 0x64006400u | (w & 15u) | ((w & 0xF0u) << 12);
        const f16x2 rr = (__builtin_bit_cast(f16x2, hb) + cm) * s2;
        wds[j] = __builtin_bit_cast(u32, rr);
    }
    u32x4 v = {wds[0], wds[1], wds[2], wds[3]};
    *(u32x4*)(w16 + ((size_t)kb * NDIM + n) * 8) = v;
}

// ---------------- main: 256x256 8-phase counted-vmcnt fp16 GEMM (T2+T3+T4+T5) ----------------
// 512 thr = 8 waves (2M x 4N), per-wave 128x64 out; BK=64; LDS 128KB = 2 dbuf x (A 32KB + B 32KB).
// dbuf d: A chunks (row*8+slot) at u16 [d*32768, +16384); B chunks (kbl*256+nl) at +16384.
// A swizzle: slot = kchunk ^ (row&7), inverse pre-applied on global src (linear gload_lds dst).
// M-frags strided: wave wm owns rows mt*32+wm*16; phase p consumes A rows [64p, 64p+64).
// Stage slots/group t (hazard-free vs consumption): p0: A1(t+1)->d^1; p1: B0(t+2)->d;
// p2: B1(t+2)->d; p3: A0(t+2)->d. vmcnt(6) once per group end => tile t+1 fully landed.
__global__ __launch_bounds__(512, 2) void gemm_8ph(
    const u16* __restrict__ x16,   // [M][K] fp16
    const u16* __restrict__ w16,   // [K/8][N][8] fp16
    const float* __restrict__ bias,
    float*       __restrict__ out)
{
    __shared__ __align__(16) u16 lds[65536];   // 128 KB

    const int tid  = threadIdx.x;
    const int wave = tid >> 6;
    const int lane = tid & 63;
    const int wm   = wave >> 2;        // 0..1
    const int wn   = wave & 3;         // 0..3
    const int quad = lane >> 4;
    const int l15  = lane & 15;
    const int l7   = l15 & 7;

    // XCD-aware bijective swizzle: 43*32 = 1376 = 8 * 172 exact
    const int bid   = blockIdx.y * 43 + blockIdx.x;
    const int swz   = (bid & 7) * 172 + (bid >> 3);
    const int n_blk = swz % 43;
    const int m_blk = swz / 43;
    const int m0    = m_blk * 256;
    const int n0    = n_blk * 256;

    // per-thread staging offsets (2 x 16B chunks per half-tile per operand)
    u32 offA[2], offB[2];
#pragma unroll
    for (int p = 0; p < 2; ++p) {
        const int c    = p * 512 + tid;        // chunk within a half (0..1023)
        const int rowh = c >> 3;               // 0..127
        const int slot = c & 7;
        const int kc   = slot ^ (rowh & 7);    // pre-swizzled global k-chunk
        offA[p] = (u32)rowh * KDIM + (u32)kc * 8;
        offB[p] = (u32)(c >> 8) * (NDIM * 8) + (u32)(n0 + (c & 255)) * 8;
    }
    const u16* xb = x16 + (size_t)m0 * KDIM;

    // ds_read bases (u16 index units)
    const u32 aBase0 = (u32)(wm * 16 + l15) * 64;
    const u32 sl0    = (u32)((quad)     ^ l7) * 8;
    const u32 sl1    = (u32)((quad + 4) ^ l7) * 8;
    const u32 bBase0 = 16384u + (u32)quad * 2048u + (u32)(wn * 64 + l15) * 8;

    f32x4 acc[8][4];
    const f32x4 zero4 = {0.f, 0.f, 0.f, 0.f};
#pragma unroll
    for (int mt = 0; mt < 8; ++mt)
#pragma unroll
        for (int nt = 0; nt < 4; ++nt) acc[mt][nt] = zero4;

#define GLD(SRC, DSTIDX)                                                       \
    __builtin_amdgcn_global_load_lds((gu32*)(const void*)(SRC),                \
                                     (su32*)(void*)(&lds[(DSTIDX)]), 16, 0, 0)

#define STAGE_A(KT, H, DD) do {                                                \
    GLD(xb + (size_t)(KT) * 64 + (H) * (128 * KDIM) + offA[0],                 \
        (u32)(DD) * 32768u + ((u32)(H) * 1024u + (u32)tid) * 8u);              \
    GLD(xb + (size_t)(KT) * 64 + (H) * (128 * KDIM) + offA[1],                 \
        (u32)(DD) * 32768u + ((u32)(H) * 1024u + 512u + (u32)tid) * 8u);       \
} while (0)

#define STAGE_B(KT, H, DD) do {                                                \
    GLD(w16 + (size_t)(KT) * (NDIM * 64) + (size_t)(H) * (NDIM * 32) + offB[0],\
        (u32)(DD) * 32768u + 16384u + ((u32)(H) * 1024u + (u32)tid) * 8u);     \
    GLD(w16 + (size_t)(KT) * (NDIM * 64) + (size_t)(H) * (NDIM * 32) + offB[1],\
        (u32)(DD) * 32768u + 16384u + ((u32)(H) * 1024u + 512u + (u32)tid) * 8u); \
} while (0)

#define DS_A(DD, MT, SL) (*(const f16x8*)&lds[(DD) * 32768u + aBase0 + (MT) * 2048u + (SL)])
#define DS_B(DD, KS, NT) (*(const f16x8*)&lds[(DD) * 32768u + bBase0 + (KS) * 8192u + (NT) * 128u])

#define MM8(MT, AK0, AK1)                                                                 \
    acc[MT][0] = __builtin_amdgcn_mfma_f32_16x16x32_f16(AK0, b00, acc[MT][0], 0, 0, 0);   \
    acc[MT][1] = __builtin_amdgcn_mfma_f32_16x16x32_f16(AK0, b01, acc[MT][1], 0, 0, 0);   \
    acc[MT][2] = __builtin_amdgcn_mfma_f32_16x16x32_f16(AK0, b02, acc[MT][2], 0, 0, 0);   \
    acc[MT][3] = __builtin_amdgcn_mfma_f32_16x16x32_f16(AK0, b03, acc[MT][3], 0, 0, 0);   \
    acc[MT][0] = __builtin_amdgcn_mfma_f32_16x16x32_f16(AK1, b10, acc[MT][0], 0, 0, 0);   \
    acc[MT][1] = __builtin_amdgcn_mfma_f32_16x16x32_f16(AK1, b11, acc[MT][1], 0, 0, 0);   \
    acc[MT][2] = __builtin_amdgcn_mfma_f32_16x16x32_f16(AK1, b12, acc[MT][2], 0, 0, 0);   \
    acc[MT][3] = __builtin_amdgcn_mfma_f32_16x16x32_f16(AK1, b13, acc[MT][3], 0, 0, 0);

#define PH_IN()  __builtin_amdgcn_sched_barrier(0);                            \
                 __builtin_amdgcn_s_barrier();                                 \
                 asm volatile("s_waitcnt lgkmcnt(0)" ::: "memory");            \
                 __builtin_amdgcn_sched_barrier(0);                            \
                 __builtin_amdgcn_s_setprio(1)

#define PH_OUT() __builtin_amdgcn_s_setprio(0);                                \
                 __builtin_amdgcn_sched_barrier(0);                            \
                 __builtin_amdgcn_s_barrier()

#define GROUP(T, D, EA1, ET2, VMTOK) do {                                      \
    /* phase 0: all 8 B-frags + A mt0,1 */                                     \
    f16x8 b00 = DS_B(D,0,0), b01 = DS_B(D,0,1), b02 = DS_B(D,0,2), b03 = DS_B(D,0,3); \
    f16x8 b10 = DS_B(D,1,0), b11 = DS_B(D,1,1), b12 = DS_B(D,1,2), b13 = DS_B(D,1,3); \
    f16x8 aa0 = DS_A(D,0,sl0), aa1 = DS_A(D,0,sl1);                            \
    f16x8 ab0 = DS_A(D,1,sl0), ab1 = DS_A(D,1,sl1);                            \
    if (EA1) STAGE_A((T) + 1, 1, (D) ^ 1);                                     \
    PH_IN(); MM8(0, aa0, aa1) MM8(1, ab0, ab1) PH_OUT();                       \
    /* phase 1: A mt2,3 */                                                     \
    aa0 = DS_A(D,2,sl0); aa1 = DS_A(D,2,sl1);                                  \
    ab0 = DS_A(D,3,sl0); ab1 = DS_A(D,3,sl1);                                  \
    if (ET2) STAGE_B((T) + 2, 0, (D));                                         \
    PH_IN(); MM8(2, aa0, aa1) MM8(3, ab0, ab1) PH_OUT();                       \
    /* phase 2: A mt4,5 */                                                     \
    aa0 = DS_A(D,4,sl0); aa1 = DS_A(D,4,sl1);                                  \
    ab0 = DS_A(D,5,sl0); ab1 = DS_A(D,5,sl1);                                  \
    if (ET2) STAGE_B((T) + 2, 1, (D));                                         \
    PH_IN(); MM8(4, aa0, aa1) MM8(5, ab0, ab1) PH_OUT();                       \
    /* phase 3: A mt6,7 */                                                     \
    aa0 = DS_A(D,6,sl0); aa1 = DS_A(D,6,sl1);                                  \
    ab0 = DS_A(D,7,sl0); ab1 = DS_A(D,7,sl1);                                  \
    if (ET2) STAGE_A((T) + 2, 0, (D));                                         \
    PH_IN(); MM8(6, aa0, aa1) MM8(7, ab0, ab1)                                 \
    __builtin_amdgcn_s_setprio(0);                                             \
    __builtin_amdgcn_sched_barrier(0);                                         \
    asm volatile("s_waitcnt " VMTOK ::: "memory");                             \
    __builtin_amdgcn_s_barrier();                                              \
} while (0)

    // ---- prologue: tile0 fully, tile1 {B0,B1,A0} -> vmcnt(6) leaves exactly those 3 ----
    STAGE_A(0, 0, 0); STAGE_A(0, 1, 0); STAGE_B(0, 0, 0); STAGE_B(0, 1, 0);
    STAGE_B(1, 0, 1); STAGE_B(1, 1, 1); STAGE_A(1, 0, 1);
    asm volatile("s_waitcnt vmcnt(6)" ::: "memory");
    __builtin_amdgcn_s_barrier();

#pragma unroll 1
    for (int t = 0; t < NKT - 2; t += 2) {
        GROUP(t,     0, 1, 1, "vmcnt(6)");
        GROUP(t + 1, 1, 1, 1, "vmcnt(6)");
    }
    GROUP(NKT - 2, 0, 1, 0, "vmcnt(0)");
    GROUP(NKT - 1, 1, 0, 0, "vmcnt(0)");

    // ---- epilogue ----
    float bv[4];
#pragma unroll
    for (int nt = 0; nt < 4; ++nt)
        bv[nt] = bias[n0 + wn * 64 + nt * 16 + l15];
#pragma unroll
    for (int mt = 0; mt < 8; ++mt) {
        const int row = m0 + mt * 32 + wm * 16 + quad * 4;   // C/D: row=quad*4+r, col=l15
#pragma unroll
        for (int nt = 0; nt < 4; ++nt) {
            const int col = n0 + wn * 64 + nt * 16 + l15;
#pragma unroll
            for (int r = 0; r < 4; ++r)
                out[(size_t)(row + r) * NDIM + col] = acc[mt][nt][r] + bv[nt];
        }
    }
#undef GLD
#undef STAGE_A
#undef STAGE_B
#undef DS_A
#undef DS_B
#undef MM8
#undef PH_IN
#undef PH_OUT
#undef GROUP
}

// ---------------- fallback (no workspace): R5 fused kernel ----------------
#define LDA  72
#define ABUF (128 * LDA)
#define BBUF 8192

__global__ __launch_bounds__(256) void int4_gemm_fb(
    const float* __restrict__ x, const int* __restrict__ wpk,
    const float* __restrict__ sc, const float* __restrict__ bias, float* __restrict__ out)
{
    __shared__ __align__(16) u16 ldsA[2 * ABUF];
    __shared__ __align__(16) u16 ldsB[2 * BBUF];

    const int tid  = threadIdx.x;
    const int wave = tid >> 6;
    const int lane = tid & 63;
    const int wm   = wave >> 1;
    const int wn   = wave & 1;
    const int quad = lane >> 4;
    const int l15  = lane & 15;
    const int bid   = blockIdx.y * 86 + blockIdx.x;
    const int swz   = (bid & 7) * 688 + (bid >> 3);
    const int n_blk = swz % 86;
    const int m_blk = swz / 86;
    const int m0    = m_blk * 128;
    const int n0    = n_blk * 128;
    const int n_local = tid & 127;
    const int half    = tid >> 7;
    const int gn      = n0 + n_local;

    f32x4 acc[4][4];
    const f32x4 zero4 = {0.f, 0.f, 0.f, 0.f};
#pragma unroll
    for (int mt = 0; mt < 4; ++mt)
#pragma unroll
        for (int nt = 0; nt < 4; ++nt) acc[mt][nt] = zero4;

    f32x4 areg[8];
    int   pw[16];
    float scur;
#pragma unroll
    for (int p = 0; p < 8; ++p) {
        const int c = p * 256 + tid;
        areg[p] = *(const f32x4*)(x + (size_t)(m0 + (c >> 4)) * KDIM + (c & 15) * 4);
    }
#pragma unroll
    for (int i = 0; i < 16; ++i) pw[i] = wpk[(half * 16 + i) * NDIM + gn];
    scur = sc[gn];
    {
        const f16 sh = (f16)scur;
        const f16x2 s2 = {sh, sh};
        const f16x2 cm = {(f16)(-1032.0f), (f16)(-1032.0f)};
#pragma unroll
        for (int q = 0; q < 4; ++q) {
            u32 wds[4];
#pragma unroll
            for (int r = 0; r < 4; ++r) {
                const u32 w = (u32)pw[q * 4 + r];
                const u32 hb = 0x64006400u | (w & 15u) | ((w & 0xF0u) << 12);
                const f16x2 rr = (__builtin_bit_cast(f16x2, hb) + cm) * s2;
                wds[r] = __builtin_bit_cast(u32, rr);
            }
            u32x4 wv = {wds[0], wds[1], wds[2], wds[3]};
            *(u32x4*)&ldsB[(half * 512 + q * 128 + n_local) * 8] = wv;
        }
#pragma unroll
        for (int p = 0; p < 8; ++p) {
            const int c = p * 256 + tid;
            u32x2 v;
            v.x = __builtin_bit_cast(u32, __builtin_amdgcn_cvt_pkrtz(areg[p][0], areg[p][1]));
            v.y = __builtin_bit_cast(u32, __builtin_amdgcn_cvt_pkrtz(areg[p][2], areg[p][3]));
            *(u32x2*)&ldsA[(c >> 4) * LDA + (c & 15) * 4] = v;
        }
    }
#pragma unroll
    for (int p = 0; p < 8; ++p) {
        const int c = p * 256 + tid;
        areg[p] = *(const f32x4*)(x + (size_t)(m0 + (c >> 4)) * KDIM + 64 + (c & 15) * 4);
    }
#pragma unroll
    for (int i = 0; i < 16; ++i) pw[i] = wpk[(32 + half * 16 + i) * NDIM + gn];
    scur = sc[gn];
    __syncthreads();

    for (int kt = 0; kt < NKT; ++kt) {
        const int cur = kt & 1;
        const u16* asrc = ldsA + cur * ABUF;
        const u16* bsrc = ldsB + cur * BBUF;
        if (kt + 1 < NKT) {
            u16* adst = ldsA + (cur ^ 1) * ABUF;
            u16* bdst = ldsB + (cur ^ 1) * BBUF;
            const f16 sh = (f16)scur;
            const f16x2 s2 = {sh, sh};
            const f16x2 cm = {(f16)(-1032.0f), (f16)(-1032.0f)};
#pragma unroll
            for (int q = 0; q < 4; ++q) {
                u32 wds[4];
#pragma unroll
                for (int r = 0; r < 4; ++r) {
                    const u32 w = (u32)pw[q * 4 + r];
                    const u32 hb = 0x64006400u | (w & 15u) | ((w & 0xF0u) << 12);
                    const f16x2 rr = (__builtin_bit_cast(f16x2, hb) + cm) * s2;
                    wds[r] = __builtin_bit_cast(u32, rr);
                }
                u32x4 wv = {wds[0], wds[1], wds[2], wds[3]};
                *(u32x4*)&bdst[(half * 512 + q * 128 + n_local) * 8] = wv;
            }
#pragma unroll
            for (int p = 0; p < 8; ++p) {
                const int c = p * 256 + tid;
                u32x2 v;
                v.x = __builtin_bit_cast(u32, __builtin_amdgcn_cvt_pkrtz(areg[p][0], areg[p][1]));
                v.y = __builtin_bit_cast(u32, __builtin_amdgcn_cvt_pkrtz(areg[p][2], areg[p][3]));
                *(u32x2*)&adst[(c >> 4) * LDA + (c & 15) * 4] = v;
            }
            if (kt + 2 < NKT) {
#pragma unroll
                for (int p = 0; p < 8; ++p) {
                    const int c = p * 256 + tid;
                    areg[p] = *(const f32x4*)(x + (size_t)(m0 + (c >> 4)) * KDIM
                                                + (kt + 2) * 64 + (c & 15) * 4);
                }
                const int kp0 = (kt + 2) * 32 + half * 16;
#pragma unroll
                for (int i = 0; i < 16; ++i) pw[i] = wpk[(kp0 + i) * NDIM + gn];
                scur = sc[((kt + 2) >> 1) * NDIM + gn];
            }
        }
#pragma unroll
        for (int ks = 0; ks < 2; ++ks) {
            f16x8 af[4], bfr[4];
#pragma unroll
            for (int mt = 0; mt < 4; ++mt)
                af[mt] = *(const f16x8*)&asrc[(wm * 64 + mt * 16 + l15) * LDA + ks * 32 + quad * 8];
#pragma unroll
            for (int nt = 0; nt < 4; ++nt)
                bfr[nt] = *(const f16x8*)&bsrc[(ks * 512 + quad * 128 + wn * 64 + nt * 16 + l15) * 8];
#pragma unroll
            for (int mt = 0; mt < 4; ++mt)
#pragma unroll
                for (int nt = 0; nt < 4; ++nt)
                    acc[mt][nt] = __builtin_amdgcn_mfma_f32_16x16x32_f16(
                        af[mt], bfr[nt], acc[mt][nt], 0, 0, 0);
        }
        if (kt + 1 < NKT) __syncthreads();
    }

    float bv[4];
#pragma unroll
    for (int nt = 0; nt < 4; ++nt)
        bv[nt] = bias[n0 + wn * 64 + nt * 16 + l15];
#pragma unroll
    for (int mt = 0; mt < 4; ++mt) {
        const int row = m0 + wm * 64 + mt * 16 + quad * 4;
#pragma unroll
        for (int nt = 0; nt < 4; ++nt) {
            const int col = n0 + wn * 64 + nt * 16 + l15;
#pragma unroll
            for (int r = 0; r < 4; ++r)
                out[(size_t)(row + r) * NDIM + col] = acc[mt][nt][r] + bv[nt];
        }
    }
}

extern "C" void kernel_launch(void* const* d_in, const int* in_sizes, int n_in,
                              void* d_out, int out_size, void* d_ws, size_t ws_size,
                              hipStream_t stream) {
    const float* x    = (const float*)d_in[0];
    const int*   wpk  = (const int*)d_in[1];
    const float* scl  = (const float*)d_in[2];
    const float* bias = (const float*)d_in[3];
    // d_in[4] = group_size (=128), baked in

    if (d_ws != nullptr && ws_size >= WS_NEEDED) {
        u16* x16 = (u16*)d_ws;
        u16* w16 = (u16*)((char*)d_ws + X16_BYTES);
        cvt_x<<<dim3(16384), dim3(256), 0, stream>>>(x, x16);
        dq_w <<<dim3(22016), dim3(256), 0, stream>>>(wpk, scl, w16);
        dim3 grid(NDIM / 256, MDIM / 256);   // 43 x 32 = 1376 = 8 * 172
        gemm_8ph<<<grid, dim3(512), 0, stream>>>(x16, w16, bias, (float*)d_out);
    } else {
        dim3 grid(NDIM / 128, MDIM / 128);
        int4_gemm_fb<<<grid, dim3(256), 0, stream>>>(x, wpk, scl, bias, (float*)d_out);
    }
}